// Round 12
// baseline (2836.705 us; speedup 1.0000x reference)
//
#include <hip/hip_runtime.h>
#include <hip/hip_bf16.h>
#include <stdint.h>

typedef __attribute__((ext_vector_type(8))) short short8;
typedef __attribute__((ext_vector_type(8))) unsigned short ushort8;
typedef __attribute__((ext_vector_type(4))) float f32x4;
typedef __attribute__((ext_vector_type(8))) __bf16 bf16x8;

#define GAS __attribute__((address_space(1)))
#define LAS __attribute__((address_space(3)))

static constexpr int Bn = 16384;   // batch
static constexpr int Hn = 1024;    // hidden
static constexpr int KT = 4096;    // IN + H + CTX (concat K)
static constexpr int NT = KT / 64; // 64 K-tiles

#define SBAR()   __builtin_amdgcn_s_barrier()
#define VMCNT(n) asm volatile("s_waitcnt vmcnt(" #n ")" ::: "memory")
#define FENCE()  asm volatile("" ::: "memory")

__device__ __forceinline__ unsigned short f2bf(float f) {
  unsigned u = __builtin_bit_cast(unsigned, f);
  u = (u + 0x7FFFu + ((u >> 16) & 1u)) >> 16;   // RNE
  return (unsigned short)u;
}

__device__ __forceinline__ float fast_sigm(float x) {
  return __builtin_amdgcn_rcpf(1.f + __expf(-x));
}
__device__ __forceinline__ float fast_tanh(float x) {
  return 1.f - 2.f * __builtin_amdgcn_rcpf(__expf(2.f * x) + 1.f);
}

// Concat-convert 3 fp32 sources (widths 1024,1024,2048) into bf16 [rows][4096].
__global__ __launch_bounds__(256) void cvt_concat_k(
    const float* __restrict__ s0, const float* __restrict__ s1,
    const float* __restrict__ s2, unsigned short* __restrict__ dst,
    long long n8) {
  long long stride = (long long)gridDim.x * blockDim.x;
  for (long long g = (long long)blockIdx.x * blockDim.x + threadIdx.x; g < n8;
       g += stride) {
    long long row = g >> 9;
    int cg = (int)(g & 511) << 3;
    const float* src;
    if (cg < 1024)      src = s0 + row * 1024 + cg;
    else if (cg < 2048) src = s1 + row * 1024 + (cg - 1024);
    else                src = s2 + row * 2048 + (cg - 2048);
    float4 f0 = *(const float4*)src;
    float4 f1 = *(const float4*)(src + 4);
    ushort8 o;
    o[0] = f2bf(f0.x); o[1] = f2bf(f0.y); o[2] = f2bf(f0.z); o[3] = f2bf(f0.w);
    o[4] = f2bf(f1.x); o[5] = f2bf(f1.y); o[6] = f2bf(f1.z); o[7] = f2bf(f1.w);
    *(ushort8*)(dst + (g << 3)) = o;
  }
}

// Pack W|U|C into 16x16x32-MFMA B-frag records — WRITE-COALESCED (r10).
__global__ __launch_bounds__(256) void cvt_pack_w(
    const float* __restrict__ s0, const float* __restrict__ s1,
    const float* __restrict__ s2, unsigned short* __restrict__ dst,
    long long ntot) {
  long long stride = (long long)gridDim.x * blockDim.x;
  for (long long g = (long long)blockIdx.x * blockDim.x + threadIdx.x; g < ntot;
       g += stride) {
    int li = (int)(g & 63);
    long long rec = g >> 6;
    int cb = (int)(rec & 255);
    int k32 = (int)(rec >> 8);
    int fr = li & 15, ksl = li >> 4;
    int row = cb * 16 + fr;            // W-concat row = gemm column
    int k0 = k32 * 32 + ksl * 8;
    const float* src;
    if (k0 < 1024)      src = s0 + (size_t)row * 1024 + k0;
    else if (k0 < 2048) src = s1 + (size_t)row * 1024 + (k0 - 1024);
    else                src = s2 + (size_t)row * 2048 + (k0 - 2048);
    float4 f0 = *(const float4*)src;
    float4 f1 = *(const float4*)(src + 4);
    ushort8 o;
    o[0] = f2bf(f0.x); o[1] = f2bf(f0.y); o[2] = f2bf(f0.z); o[3] = f2bf(f0.w);
    o[4] = f2bf(f1.x); o[5] = f2bf(f1.y); o[6] = f2bf(f1.z); o[7] = f2bf(f1.w);
    *(ushort8*)(dst + (g << 3)) = o;
  }
}

// 256x256 GEMM + fused LSTM. 16x16x32 MFMA, 8 waves (2M x 4N).  [r10 base]
// r12 change: WAVE PHASE-STAGGER. All 8 waves leave the tile-top barrier in
// phase, so LDS-read bursts and MFMA bursts collide per-pipe (sum not max).
// Odd waves now run the 4 independent intra-tile phases in rotated order
// (2,3,0,1): at any instant half the waves feed the LDS pipe while the other
// half feed the MFMA pipe. Static phase macros keyed on wave-uniform wid&1
// (no dynamic acc indexing). Stage/prefetch hooks keyed to sequence POSITION
// (B at pos1, A-stage at pos3) -> per-wave VMEM count/order identical to the
// audited r10 ledger: ONE {VMCNT(12); s_barrier} per tile; A staged 2 tiles
// ahead into 3 rotating 32KB buffers; B frag-major from global, 1 tile ahead.
__global__ __launch_bounds__(512, 2) void lstm_gemm(
    const unsigned short* __restrict__ X, const unsigned short* __restrict__ Wp,
    const float* __restrict__ bias, const float* __restrict__ c0,
    float* __restrict__ out_c, float* __restrict__ out_h) {
  extern __shared__ char smem[];  // 3 x 32KB A buffers

  int bid = blockIdx.x;
  int swz = (bid & 7) * 128 + (bid >> 3);  // 1024 blocks, 8 XCDs, bijective
  int mblk = swz >> 4, cblk = swz & 15;    // 16 consecutive share A-panel
  int brow0 = mblk * 256;
  int hcol0 = cblk * 64;

  int tid = threadIdx.x;
  int lane = tid & 63, wid = tid >> 6;
  int wr = wid >> 2, wc = wid & 3;  // 2M x 4N wave grid

  const char* Xc = (const char*)X;
  const char* Wpc = (const char*)Wp;

  // ---- A staging: inverse-swizzled global source, linear LDS dest ----
  int rr = tid >> 3;                                        // 0..63
  uint32_t cbyte = (uint32_t)(((tid & 7) * 16) ^ ((rr & 7) << 4));
  uint32_t aoffj[4];
#pragma unroll
  for (int j = 0; j < 4; ++j)
    aoffj[j] = (uint32_t)(brow0 + j * 64 + rr) * (KT * 2) + cbyte;

  auto stage_A = [&](int tt, int dbuf) {   // 32KB = 4 x global_load_lds
    int ts = tt < NT ? tt : NT - 1;
#pragma unroll
    for (int j = 0; j < 4; ++j) {
      const char* src = Xc + aoffj[j] + (uint32_t)ts * 128u;
      char* dst = smem + dbuf * 32768 + j * 8192 + wid * 1024;
      __builtin_amdgcn_global_load_lds((const GAS unsigned int*)src,
                                       (LAS unsigned int*)dst, 16, 0, 0);
    }
  };

  // ---- A ds_read swizzled offsets ----
  int kg = (lane >> 4) << 4;
  int sw = (lane & 7) << 4;
  int koff0 = kg ^ sw;
  int koff1 = (64 + kg) ^ sw;
  int fr = lane & 15;

  // ---- B frag-major per-lane base pointers (gate n) ----
  const char* bbp[4];
#pragma unroll
  for (int n = 0; n < 4; ++n) {
    int cb = n * 64 + cblk * 4 + wc;
    bbp[n] = Wpc + ((size_t)cb * 64 + lane) * 16;
  }

  f32x4 acc[8][4] = {};
  short8 bfrE[4][2], bfrO[4][2];   // B frag parity sets [n][k-slice]

  // ---- prologue: A(0); fence; B(0)->E + A(1)   (16 VMEM, A(0) oldest) ----
  stage_A(0, 0);
  FENCE();
#pragma unroll
  for (int n = 0; n < 4; ++n) {
    bfrE[n][0] = *(const short8*)(bbp[n]);
    bfrE[n][1] = *(const short8*)(bbp[n] + 262144);
  }
  stage_A(1, 1);

  int bufA = 0;

  // One phase: m-frags 2Q,2Q+1. POS = position in this wave's sequence
  // (hooks keyed to POS so the per-wave VMEM ledger matches r10 exactly).
#define PH(Q_, POS_, T_, BC, BN)                                              \
  {                                                                           \
    int ab = pb + ((2 * (Q_) + wr) * 32 + fr) * 128;                          \
    short8 a0 = *(const short8*)(smem + ab + koff0);                          \
    short8 a1 = *(const short8*)(smem + ab + koff1);                          \
    short8 a2 = *(const short8*)(smem + ab + 2048 + koff0);                   \
    short8 a3 = *(const short8*)(smem + ab + 2048 + koff1);                   \
    if ((POS_) == 1) {  /* coalesced B prefetch for T_+1, other parity */     \
      int ts = (T_) + 1 < NT ? (T_) + 1 : NT - 1;                             \
      size_t tb = (size_t)(2 * ts) * 262144u;                                 \
      _Pragma("unroll")                                                       \
      for (int n = 0; n < 4; ++n) {                                           \
        BN[n][0] = *(const short8*)(bbp[n] + tb);                             \
        BN[n][1] = *(const short8*)(bbp[n] + tb + 262144);                    \
      }                                                                       \
    }                                                                         \
    if ((POS_) == 3) stage_A((T_) + 2, stg);                                  \
    __builtin_amdgcn_s_setprio(1);                                            \
    _Pragma("unroll")                                                         \
    for (int n = 0; n < 4; ++n) {                                             \
      acc[2 * (Q_)][n] = __builtin_amdgcn_mfma_f32_16x16x32_bf16(             \
          __builtin_bit_cast(bf16x8, a0), __builtin_bit_cast(bf16x8, BC[n][0]),\
          acc[2 * (Q_)][n], 0, 0, 0);                                         \
      acc[2 * (Q_) + 1][n] = __builtin_amdgcn_mfma_f32_16x16x32_bf16(         \
          __builtin_bit_cast(bf16x8, a2), __builtin_bit_cast(bf16x8, BC[n][0]),\
          acc[2 * (Q_) + 1][n], 0, 0, 0);                                     \
    }                                                                         \
    _Pragma("unroll")                                                         \
    for (int n = 0; n < 4; ++n) {                                             \
      acc[2 * (Q_)][n] = __builtin_amdgcn_mfma_f32_16x16x32_bf16(             \
          __builtin_bit_cast(bf16x8, a1), __builtin_bit_cast(bf16x8, BC[n][1]),\
          acc[2 * (Q_)][n], 0, 0, 0);                                         \
      acc[2 * (Q_) + 1][n] = __builtin_amdgcn_mfma_f32_16x16x32_bf16(         \
          __builtin_bit_cast(bf16x8, a3), __builtin_bit_cast(bf16x8, BC[n][1]),\
          acc[2 * (Q_) + 1][n], 0, 0, 0);                                     \
    }                                                                         \
    __builtin_amdgcn_s_setprio(0);                                            \
  }

#define TILE(T_, BC, BN)                                                      \
  {                                                                           \
    VMCNT(12);                                                                \
    SBAR();                                                                   \
    int pb = bufA * 32768;                                                    \
    int stg = bufA + 2; if (stg >= 3) stg -= 3;                               \
    if ((wid & 1) == 0) {                                                     \
      PH(0, 0, T_, BC, BN) PH(1, 1, T_, BC, BN)                               \
      PH(2, 2, T_, BC, BN) PH(3, 3, T_, BC, BN)                               \
    } else {                                                                  \
      PH(2, 0, T_, BC, BN) PH(3, 1, T_, BC, BN)                               \
      PH(0, 2, T_, BC, BN) PH(1, 3, T_, BC, BN)                               \
    }                                                                         \
    bufA = bufA + 1; if (bufA >= 3) bufA = 0;                                 \
  }

  for (int t = 0; t < NT; t += 2) {
    TILE(t, bfrE, bfrO)
    TILE(t + 1, bfrO, bfrE)
  }
#undef TILE
#undef PH

  // ---- fused LSTM epilogue (acc[m][n]: n = gate) ----
  int col = hcol0 + wc * 16 + fr;
  float bi = bias[col], bf_ = bias[1024 + col];
  float bo = bias[2048 + col], bc = bias[3072 + col];
#pragma unroll
  for (int m = 0; m < 8; ++m) {
    int row0 = brow0 + (2 * (m >> 1) + wr) * 32 + (m & 1) * 16 + ((lane >> 4) << 2);
#pragma unroll
    for (int j = 0; j < 4; ++j) {
      size_t idx = (size_t)(row0 + j) * 1024 + col;
      float i_ = fast_sigm(acc[m][0][j] + bi);
      float f_ = fast_sigm(acc[m][1][j] + bf_);
      float o_ = fast_sigm(acc[m][2][j] + bo);
      float ch = fast_tanh(acc[m][3][j] + bc);
      float cn = i_ * ch + f_ * c0[idx];
      out_c[idx] = cn;
      out_h[idx] = o_ * fast_tanh(cn);
    }
  }
}

// Fallback if ws too small (not expected; ws >= 160MB confirmed in round 1).
__global__ __launch_bounds__(256) void lstm_naive(
    const float* __restrict__ y, const float* __restrict__ ctx,
    const float* __restrict__ c0, const float* __restrict__ h0,
    const float* __restrict__ W, const float* __restrict__ U,
    const float* __restrict__ C, const float* __restrict__ b,
    float* __restrict__ out_c, float* __restrict__ out_h) {
  size_t t = (size_t)blockIdx.x * blockDim.x + threadIdx.x;
  if (t >= (size_t)Bn * Hn) return;
  int row = (int)(t >> 10), col = (int)(t & 1023);
  float g[4];
#pragma unroll
  for (int gg = 0; gg < 4; ++gg) {
    int wrow = gg * 1024 + col;
    float s = b[wrow];
    const float* yr = y + (size_t)row * 1024;
    const float* Wr = W + (size_t)wrow * 1024;
    for (int k = 0; k < 1024; ++k) s += yr[k] * Wr[k];
    const float* hr = h0 + (size_t)row * 1024;
    const float* Ur = U + (size_t)wrow * 1024;
    for (int k = 0; k < 1024; ++k) s += hr[k] * Ur[k];
    const float* cr = ctx + (size_t)row * 2048;
    const float* Cr = C + (size_t)wrow * 2048;
    for (int k = 0; k < 2048; ++k) s += cr[k] * Cr[k];
    g[gg] = s;
  }
  float i_ = fast_sigm(g[0]), f_ = fast_sigm(g[1]);
  float o_ = fast_sigm(g[2]), ch = fast_tanh(g[3]);
  float cn = i_ * ch + f_ * c0[t];
  out_c[t] = cn;
  out_h[t] = o_ * fast_tanh(cn);
}

extern "C" void kernel_launch(void* const* d_in, const int* in_sizes, int n_in,
                              void* d_out, int out_size, void* d_ws, size_t ws_size,
                              hipStream_t stream) {
  const float* y   = (const float*)d_in[0];
  const float* ctx = (const float*)d_in[1];
  const float* c0  = (const float*)d_in[2];
  const float* h0  = (const float*)d_in[3];
  const float* W   = (const float*)d_in[4];
  const float* U   = (const float*)d_in[5];
  const float* C   = (const float*)d_in[6];
  const float* b   = (const float*)d_in[7];
  float* out = (float*)d_out;
  float* out_c = out;
  float* out_h = out + (size_t)Bn * Hn;

  const size_t needX = (size_t)Bn * KT * 2;
  const size_t needW = (size_t)(4 * Hn) * KT * 2;

  if (ws_size >= needX + needW) {
    unsigned short* Xb = (unsigned short*)d_ws;
    unsigned short* Wb = (unsigned short*)((char*)d_ws + needX);
    cvt_concat_k<<<2048, 256, 0, stream>>>(y, h0, ctx, Xb, (long long)Bn * 512);
    cvt_pack_w<<<2048, 256, 0, stream>>>(W, U, C, Wb,
                                         (long long)(4 * Hn) * KT / 8);
    (void)hipFuncSetAttribute((const void*)lstm_gemm,
                              hipFuncAttributeMaxDynamicSharedMemorySize, 98304);
    lstm_gemm<<<1024, 512, 98304, stream>>>(Xb, Wb, b, c0, out_c, out_h);
  } else {
    lstm_naive<<<(Bn * Hn + 255) / 256, 256, 0, stream>>>(y, ctx, c0, h0, W, U, C,
                                                          b, out_c, out_h);
  }
}

// Round 13
// 759.075 us; speedup vs baseline: 3.7371x; 3.7371x over previous
//
#include <hip/hip_runtime.h>
#include <hip/hip_bf16.h>
#include <stdint.h>

typedef __attribute__((ext_vector_type(8))) short short8;
typedef __attribute__((ext_vector_type(8))) unsigned short ushort8;
typedef __attribute__((ext_vector_type(4))) float f32x4;
typedef __attribute__((ext_vector_type(8))) __bf16 bf16x8;

#define GAS __attribute__((address_space(1)))
#define LAS __attribute__((address_space(3)))

static constexpr int Bn = 16384;   // batch
static constexpr int Hn = 1024;    // hidden
static constexpr int KT = 4096;    // IN + H + CTX (concat K)
static constexpr int NT = KT / 64; // 64 K-tiles

#define SBAR()   __builtin_amdgcn_s_barrier()
#define VMCNT(n) asm volatile("s_waitcnt vmcnt(" #n ")" ::: "memory")
#define FENCE()  asm volatile("" ::: "memory")

__device__ __forceinline__ unsigned short f2bf(float f) {
  unsigned u = __builtin_bit_cast(unsigned, f);
  u = (u + 0x7FFFu + ((u >> 16) & 1u)) >> 16;   // RNE
  return (unsigned short)u;
}

__device__ __forceinline__ float fast_sigm(float x) {
  return __builtin_amdgcn_rcpf(1.f + __expf(-x));
}
__device__ __forceinline__ float fast_tanh(float x) {
  return 1.f - 2.f * __builtin_amdgcn_rcpf(__expf(2.f * x) + 1.f);
}

// Concat-convert 3 fp32 sources (widths 1024,1024,2048) into bf16 [rows][4096].
__global__ __launch_bounds__(256) void cvt_concat_k(
    const float* __restrict__ s0, const float* __restrict__ s1,
    const float* __restrict__ s2, unsigned short* __restrict__ dst,
    long long n8) {
  long long stride = (long long)gridDim.x * blockDim.x;
  for (long long g = (long long)blockIdx.x * blockDim.x + threadIdx.x; g < n8;
       g += stride) {
    long long row = g >> 9;
    int cg = (int)(g & 511) << 3;
    const float* src;
    if (cg < 1024)      src = s0 + row * 1024 + cg;
    else if (cg < 2048) src = s1 + row * 1024 + (cg - 1024);
    else                src = s2 + row * 2048 + (cg - 2048);
    float4 f0 = *(const float4*)src;
    float4 f1 = *(const float4*)(src + 4);
    ushort8 o;
    o[0] = f2bf(f0.x); o[1] = f2bf(f0.y); o[2] = f2bf(f0.z); o[3] = f2bf(f0.w);
    o[4] = f2bf(f1.x); o[5] = f2bf(f1.y); o[6] = f2bf(f1.z); o[7] = f2bf(f1.w);
    *(ushort8*)(dst + (g << 3)) = o;
  }
}

// Pack W|U|C into 16x16x32-MFMA B-frag records — WRITE-COALESCED (r10).
__global__ __launch_bounds__(256) void cvt_pack_w(
    const float* __restrict__ s0, const float* __restrict__ s1,
    const float* __restrict__ s2, unsigned short* __restrict__ dst,
    long long ntot) {
  long long stride = (long long)gridDim.x * blockDim.x;
  for (long long g = (long long)blockIdx.x * blockDim.x + threadIdx.x; g < ntot;
       g += stride) {
    int li = (int)(g & 63);
    long long rec = g >> 6;
    int cb = (int)(rec & 255);
    int k32 = (int)(rec >> 8);
    int fr = li & 15, ksl = li >> 4;
    int row = cb * 16 + fr;            // W-concat row = gemm column
    int k0 = k32 * 32 + ksl * 8;
    const float* src;
    if (k0 < 1024)      src = s0 + (size_t)row * 1024 + k0;
    else if (k0 < 2048) src = s1 + (size_t)row * 1024 + (k0 - 1024);
    else                src = s2 + (size_t)row * 2048 + (k0 - 2048);
    float4 f0 = *(const float4*)src;
    float4 f1 = *(const float4*)(src + 4);
    ushort8 o;
    o[0] = f2bf(f0.x); o[1] = f2bf(f0.y); o[2] = f2bf(f0.z); o[3] = f2bf(f0.w);
    o[4] = f2bf(f1.x); o[5] = f2bf(f1.y); o[6] = f2bf(f1.z); o[7] = f2bf(f1.w);
    *(ushort8*)(dst + (g << 3)) = o;
  }
}

// 256x256 GEMM + fused LSTM. 16x16x32 MFMA.
// r13 change: 16 waves x 1024 threads (4M x 4N), wave = 64x64, acc[4][4]=64
// regs -> total/wave <= 128 -> 4 waves/SIMD (vs r10's 2). Doubled wave
// residency lets LDS-read bursts, B L2 loads, and MFMA co-schedule (m114).
// A: LDS via global_load_lds, 3 rotating 32KB buffers, staged 2 tiles ahead,
//    st_16x32 both-sides swizzle (conflict-free, r2-r10).
// B: frag-major packed global, SINGLE register set with full-tile prefetch:
//    B(t+1) loads issue AFTER the last MFMA reading bfr (WAR pins order).
// Ledger (in-order VMEM retirement; FENCE pins issue order):
//    per tile issue: [MFMAs] -> B(t+1) x8 -> stage_A(t+2) x2.
//    outstanding at tile top = A(t)2 + B(t)8 + A(t+1)2 = 12
//    -> VMCNT(10) retires exactly A(t); compiler's vmcnt before q0 MFMA
//    retires B(t) keeping A(t+1) in flight. Never vmcnt(0) mid-loop.
// ONE barrier per tile. Grid: 1024 blocks, A-panel-share + XCD swizzle.
__global__ __launch_bounds__(1024, 4) void lstm_gemm(
    const unsigned short* __restrict__ X, const unsigned short* __restrict__ Wp,
    const float* __restrict__ bias, const float* __restrict__ c0,
    float* __restrict__ out_c, float* __restrict__ out_h) {
  extern __shared__ char smem[];  // 3 x 32KB A buffers

  int bid = blockIdx.x;
  int swz = (bid & 7) * 128 + (bid >> 3);  // 1024 blocks, 8 XCDs, bijective
  int mblk = swz >> 4, cblk = swz & 15;    // 16 consecutive share A-panel
  int brow0 = mblk * 256;
  int hcol0 = cblk * 64;

  int tid = threadIdx.x;
  int lane = tid & 63, wid = tid >> 6;     // wid 0..15
  int wr = wid >> 2, wc = wid & 3;         // 4M x 4N wave grid

  const char* Xc = (const char*)X;
  const char* Wpc = (const char*)Wp;

  // ---- A staging: inverse-swizzled global source, linear LDS dest ----
  int rr = tid >> 3;                       // 0..127
  uint32_t cbyte = (uint32_t)(((tid & 7) * 16) ^ ((rr & 7) << 4));
  uint32_t aoffj[2];
#pragma unroll
  for (int j = 0; j < 2; ++j)
    aoffj[j] = (uint32_t)(brow0 + j * 128 + rr) * (KT * 2) + cbyte;

  auto stage_A = [&](int tt, int dbuf) {   // 32KB = 2 x global_load_lds
    int ts = tt < NT ? tt : NT - 1;
#pragma unroll
    for (int j = 0; j < 2; ++j) {
      const char* src = Xc + aoffj[j] + (uint32_t)ts * 128u;
      char* dst = smem + dbuf * 32768 + j * 16384 + wid * 1024;
      __builtin_amdgcn_global_load_lds((const GAS unsigned int*)src,
                                       (LAS unsigned int*)dst, 16, 0, 0);
    }
  };

  // ---- A ds_read swizzled offsets ----
  int kg = (lane >> 4) << 4;
  int sw = (lane & 7) << 4;
  int koff0 = kg ^ sw;
  int koff1 = (64 + kg) ^ sw;
  int fr = lane & 15;

  // ---- B frag-major per-lane base pointers (gate n) ----
  const char* bbp[4];
#pragma unroll
  for (int n = 0; n < 4; ++n) {
    int cb = n * 64 + cblk * 4 + wc;
    bbp[n] = Wpc + ((size_t)cb * 64 + lane) * 16;
  }

  f32x4 acc[4][4] = {};          // [m][n=gate], 64 regs
  short8 bfr[4][2];              // single B set [n][k-slice]

  // ---- prologue: A(0); B(0); A(1)  (12 VMEM, exact steady-state order) ----
  stage_A(0, 0);
  FENCE();
#pragma unroll
  for (int n = 0; n < 4; ++n) {
    bfr[n][0] = *(const short8*)(bbp[n]);
    bfr[n][1] = *(const short8*)(bbp[n] + 262144);
  }
  FENCE();
  stage_A(1, 1);

  int bufA = 0;

  for (int t = 0; t < NT; ++t) {
    VMCNT(10);                   // retire A(t); keep B(t)8 + A(t+1)2 in flight
    SBAR();
    int pb = bufA * 32768;
    int stg = bufA + 2; if (stg >= 3) stg -= 3;
#pragma unroll
    for (int m = 0; m < 4; ++m) {
      int ab = pb + ((wr * 4 + m) * 16 + fr) * 128;
      short8 a0 = *(const short8*)(smem + ab + koff0);
      short8 a1 = *(const short8*)(smem + ab + koff1);
      __builtin_amdgcn_s_setprio(1);
#pragma unroll
      for (int n = 0; n < 4; ++n)
        acc[m][n] = __builtin_amdgcn_mfma_f32_16x16x32_bf16(
            __builtin_bit_cast(bf16x8, a0), __builtin_bit_cast(bf16x8, bfr[n][0]),
            acc[m][n], 0, 0, 0);
#pragma unroll
      for (int n = 0; n < 4; ++n)
        acc[m][n] = __builtin_amdgcn_mfma_f32_16x16x32_bf16(
            __builtin_bit_cast(bf16x8, a1), __builtin_bit_cast(bf16x8, bfr[n][1]),
            acc[m][n], 0, 0, 0);
      __builtin_amdgcn_s_setprio(0);
    }
    // B(t+1) into the SAME regs — after last bfr-reading MFMA (WAR-ordered).
    {
      int ts = t + 1 < NT ? t + 1 : NT - 1;
      size_t tb = (size_t)(2 * ts) * 262144u;
      FENCE();
#pragma unroll
      for (int n = 0; n < 4; ++n) {
        bfr[n][0] = *(const short8*)(bbp[n] + tb);
        bfr[n][1] = *(const short8*)(bbp[n] + tb + 262144);
      }
      FENCE();
    }
    stage_A(t + 2, stg);         // newest VMEM: A(t+2)
    bufA = bufA + 1; if (bufA >= 3) bufA = 0;
  }

  // ---- fused LSTM epilogue (acc[m][n]: n = gate) ----
  int col = hcol0 + wc * 16 + fr;
  float bi = bias[col], bf_ = bias[1024 + col];
  float bo = bias[2048 + col], bc = bias[3072 + col];
#pragma unroll
  for (int m = 0; m < 4; ++m) {
    int row0 = brow0 + (wr * 4 + m) * 16 + ((lane >> 4) << 2);
#pragma unroll
    for (int j = 0; j < 4; ++j) {
      size_t idx = (size_t)(row0 + j) * 1024 + col;
      float i_ = fast_sigm(acc[m][0][j] + bi);
      float f_ = fast_sigm(acc[m][1][j] + bf_);
      float o_ = fast_sigm(acc[m][2][j] + bo);
      float ch = fast_tanh(acc[m][3][j] + bc);
      float cn = i_ * ch + f_ * c0[idx];
      out_c[idx] = cn;
      out_h[idx] = o_ * fast_tanh(cn);
    }
  }
}

// Fallback if ws too small (not expected; ws >= 160MB confirmed in round 1).
__global__ __launch_bounds__(256) void lstm_naive(
    const float* __restrict__ y, const float* __restrict__ ctx,
    const float* __restrict__ c0, const float* __restrict__ h0,
    const float* __restrict__ W, const float* __restrict__ U,
    const float* __restrict__ C, const float* __restrict__ b,
    float* __restrict__ out_c, float* __restrict__ out_h) {
  size_t t = (size_t)blockIdx.x * blockDim.x + threadIdx.x;
  if (t >= (size_t)Bn * Hn) return;
  int row = (int)(t >> 10), col = (int)(t & 1023);
  float g[4];
#pragma unroll
  for (int gg = 0; gg < 4; ++gg) {
    int wrow = gg * 1024 + col;
    float s = b[wrow];
    const float* yr = y + (size_t)row * 1024;
    const float* Wr = W + (size_t)wrow * 1024;
    for (int k = 0; k < 1024; ++k) s += yr[k] * Wr[k];
    const float* hr = h0 + (size_t)row * 1024;
    const float* Ur = U + (size_t)wrow * 1024;
    for (int k = 0; k < 1024; ++k) s += hr[k] * Ur[k];
    const float* cr = ctx + (size_t)row * 2048;
    const float* Cr = C + (size_t)wrow * 2048;
    for (int k = 0; k < 2048; ++k) s += cr[k] * Cr[k];
    g[gg] = s;
  }
  float i_ = fast_sigm(g[0]), f_ = fast_sigm(g[1]);
  float o_ = fast_sigm(g[2]), ch = fast_tanh(g[3]);
  float cn = i_ * ch + f_ * c0[t];
  out_c[t] = cn;
  out_h[t] = o_ * fast_tanh(cn);
}

extern "C" void kernel_launch(void* const* d_in, const int* in_sizes, int n_in,
                              void* d_out, int out_size, void* d_ws, size_t ws_size,
                              hipStream_t stream) {
  const float* y   = (const float*)d_in[0];
  const float* ctx = (const float*)d_in[1];
  const float* c0  = (const float*)d_in[2];
  const float* h0  = (const float*)d_in[3];
  const float* W   = (const float*)d_in[4];
  const float* U   = (const float*)d_in[5];
  const float* C   = (const float*)d_in[6];
  const float* b   = (const float*)d_in[7];
  float* out = (float*)d_out;
  float* out_c = out;
  float* out_h = out + (size_t)Bn * Hn;

  const size_t needX = (size_t)Bn * KT * 2;
  const size_t needW = (size_t)(4 * Hn) * KT * 2;

  if (ws_size >= needX + needW) {
    unsigned short* Xb = (unsigned short*)d_ws;
    unsigned short* Wb = (unsigned short*)((char*)d_ws + needX);
    cvt_concat_k<<<2048, 256, 0, stream>>>(y, h0, ctx, Xb, (long long)Bn * 512);
    cvt_pack_w<<<2048, 256, 0, stream>>>(W, U, C, Wb,
                                         (long long)(4 * Hn) * KT / 8);
    (void)hipFuncSetAttribute((const void*)lstm_gemm,
                              hipFuncAttributeMaxDynamicSharedMemorySize, 98304);
    lstm_gemm<<<1024, 1024, 98304, stream>>>(Xb, Wb, b, c0, out_c, out_h);
  } else {
    lstm_naive<<<(Bn * Hn + 255) / 256, 256, 0, stream>>>(y, ctx, c0, h0, W, U, C,
                                                          b, out_c, out_h);
  }
}

// Round 14
// 604.414 us; speedup vs baseline: 4.6933x; 1.2559x over previous
//
#include <hip/hip_runtime.h>
#include <hip/hip_bf16.h>
#include <stdint.h>

typedef __attribute__((ext_vector_type(8))) short short8;
typedef __attribute__((ext_vector_type(8))) unsigned short ushort8;
typedef __attribute__((ext_vector_type(4))) float f32x4;
typedef __attribute__((ext_vector_type(8))) __bf16 bf16x8;

#define GAS __attribute__((address_space(1)))
#define LAS __attribute__((address_space(3)))

static constexpr int Bn = 16384;   // batch
static constexpr int Hn = 1024;    // hidden
static constexpr int KT = 4096;    // IN + H + CTX (concat K)
static constexpr int NT = KT / 64; // 64 K-tiles (even)

#define SBAR()   __builtin_amdgcn_s_barrier()
#define VMCNT(n) asm volatile("s_waitcnt vmcnt(" #n ")" ::: "memory")
#define FENCE()  asm volatile("" ::: "memory")

__device__ __forceinline__ unsigned short f2bf(float f) {
  unsigned u = __builtin_bit_cast(unsigned, f);
  u = (u + 0x7FFFu + ((u >> 16) & 1u)) >> 16;   // RNE
  return (unsigned short)u;
}

__device__ __forceinline__ float fast_sigm(float x) {
  return __builtin_amdgcn_rcpf(1.f + __expf(-x));
}
__device__ __forceinline__ float fast_tanh(float x) {
  return 1.f - 2.f * __builtin_amdgcn_rcpf(__expf(2.f * x) + 1.f);
}

// Concat-convert 3 fp32 sources (widths 1024,1024,2048) into bf16 [rows][4096].
__global__ __launch_bounds__(256) void cvt_concat_k(
    const float* __restrict__ s0, const float* __restrict__ s1,
    const float* __restrict__ s2, unsigned short* __restrict__ dst,
    long long n8) {
  long long stride = (long long)gridDim.x * blockDim.x;
  for (long long g = (long long)blockIdx.x * blockDim.x + threadIdx.x; g < n8;
       g += stride) {
    long long row = g >> 9;
    int cg = (int)(g & 511) << 3;
    const float* src;
    if (cg < 1024)      src = s0 + row * 1024 + cg;
    else if (cg < 2048) src = s1 + row * 1024 + (cg - 1024);
    else                src = s2 + row * 2048 + (cg - 2048);
    float4 f0 = *(const float4*)src;
    float4 f1 = *(const float4*)(src + 4);
    ushort8 o;
    o[0] = f2bf(f0.x); o[1] = f2bf(f0.y); o[2] = f2bf(f0.z); o[3] = f2bf(f0.w);
    o[4] = f2bf(f1.x); o[5] = f2bf(f1.y); o[6] = f2bf(f1.z); o[7] = f2bf(f1.w);
    *(ushort8*)(dst + (g << 3)) = o;
  }
}

// Pack W|U|C into 16x16x32-MFMA B-frag records — WRITE-COALESCED (r10).
__global__ __launch_bounds__(256) void cvt_pack_w(
    const float* __restrict__ s0, const float* __restrict__ s1,
    const float* __restrict__ s2, unsigned short* __restrict__ dst,
    long long ntot) {
  long long stride = (long long)gridDim.x * blockDim.x;
  for (long long g = (long long)blockIdx.x * blockDim.x + threadIdx.x; g < ntot;
       g += stride) {
    int li = (int)(g & 63);
    long long rec = g >> 6;
    int cb = (int)(rec & 255);
    int k32 = (int)(rec >> 8);
    int fr = li & 15, ksl = li >> 4;
    int row = cb * 16 + fr;            // W-concat row = gemm column
    int k0 = k32 * 32 + ksl * 8;
    const float* src;
    if (k0 < 1024)      src = s0 + (size_t)row * 1024 + k0;
    else if (k0 < 2048) src = s1 + (size_t)row * 1024 + (k0 - 1024);
    else                src = s2 + (size_t)row * 2048 + (k0 - 2048);
    float4 f0 = *(const float4*)src;
    float4 f1 = *(const float4*)(src + 4);
    ushort8 o;
    o[0] = f2bf(f0.x); o[1] = f2bf(f0.y); o[2] = f2bf(f0.z); o[3] = f2bf(f0.w);
    o[4] = f2bf(f1.x); o[5] = f2bf(f1.y); o[6] = f2bf(f1.z); o[7] = f2bf(f1.w);
    *(ushort8*)(dst + (g << 3)) = o;
  }
}

// 256x256 GEMM + fused LSTM. 16x16x32 MFMA, 8 waves (2M x 4N).  [r10 base]
// r14 change: BARRIER EVERY 2 TILES with 4 rotating A-buffers (128KB LDS).
// r10 resyncs all waves every tile -> LDS-read bursts and MFMA bursts run in
// lockstep (pipes sum, not overlap). Even-tile-only barriers allow +/-1-tile
// wave skew so one wave's ds_reads ride under another's MFMAs.
// Audited ledger (in-order VMEM retirement; per tile issue: stage_A(t+2) at
// q0, B(t+1)x8 at q1):
//   top of EVEN tile t: outstanding = A(t+1)4 + B(t)8  (A(t) already retired
//   via B(t-1) consumption). VMCNT(8) retires A(t) AND A(t+1); barrier
//   publishes both tiles' A to all waves -> odd tiles need no gate/barrier.
//   Buffer overwrite at t targets (t+2)&3 = (t-2)&3: its readers are >=2
//   tiles back, fenced by the even barrier; max skew 1 tile -> safe.
// A staged 2 tiles ahead (r10 depth); B parity double-buffer (r10); never
// vmcnt(0) mid-loop. Grid: A-panel-share + XCD-bijective swizzle.
__global__ __launch_bounds__(512, 2) void lstm_gemm(
    const unsigned short* __restrict__ X, const unsigned short* __restrict__ Wp,
    const float* __restrict__ bias, const float* __restrict__ c0,
    float* __restrict__ out_c, float* __restrict__ out_h) {
  extern __shared__ char smem[];  // 4 x 32KB A buffers

  int bid = blockIdx.x;
  int swz = (bid & 7) * 128 + (bid >> 3);  // 1024 blocks, 8 XCDs, bijective
  int mblk = swz >> 4, cblk = swz & 15;    // 16 consecutive share A-panel
  int brow0 = mblk * 256;
  int hcol0 = cblk * 64;

  int tid = threadIdx.x;
  int lane = tid & 63, wid = tid >> 6;
  int wr = wid >> 2, wc = wid & 3;  // 2M x 4N wave grid

  const char* Xc = (const char*)X;
  const char* Wpc = (const char*)Wp;

  // ---- A staging: inverse-swizzled global source, linear LDS dest ----
  int rr = tid >> 3;                                        // 0..63
  uint32_t cbyte = (uint32_t)(((tid & 7) * 16) ^ ((rr & 7) << 4));
  uint32_t aoffj[4];
#pragma unroll
  for (int j = 0; j < 4; ++j)
    aoffj[j] = (uint32_t)(brow0 + j * 64 + rr) * (KT * 2) + cbyte;

  auto stage_A = [&](int tt) {             // 32KB = 4 x global_load_lds
    int ts = tt < NT ? tt : NT - 1;
    int dbuf = tt & 3;
#pragma unroll
    for (int j = 0; j < 4; ++j) {
      const char* src = Xc + aoffj[j] + (uint32_t)ts * 128u;
      char* dst = smem + dbuf * 32768 + j * 8192 + wid * 1024;
      __builtin_amdgcn_global_load_lds((const GAS unsigned int*)src,
                                       (LAS unsigned int*)dst, 16, 0, 0);
    }
  };

  // ---- A ds_read swizzled offsets ----
  int kg = (lane >> 4) << 4;
  int sw = (lane & 7) << 4;
  int koff0 = kg ^ sw;
  int koff1 = (64 + kg) ^ sw;
  int fr = lane & 15;

  // ---- B frag-major per-lane base pointers (gate n) ----
  const char* bbp[4];
#pragma unroll
  for (int n = 0; n < 4; ++n) {
    int cb = n * 64 + cblk * 4 + wc;
    bbp[n] = Wpc + ((size_t)cb * 64 + lane) * 16;
  }

  f32x4 acc[8][4] = {};
  short8 bfrE[4][2], bfrO[4][2];   // B frag parity sets [n][k-slice]

  // ---- prologue: A(0); A(1); B(0)->E   (16 VMEM; newest 8 = B(0)) ----
  stage_A(0);
  stage_A(1);
  FENCE();
#pragma unroll
  for (int n = 0; n < 4; ++n) {
    bfrE[n][0] = *(const short8*)(bbp[n]);
    bfrE[n][1] = *(const short8*)(bbp[n] + 262144);
  }

  // TILE body: BAR_ = 1 -> even tile (gate + barrier at top).
#define TILE(T_, BAR_, BC, BN)                                                \
  {                                                                           \
    if (BAR_) { VMCNT(8); SBAR(); }                                           \
    int pb = ((T_) & 3) * 32768;                                              \
    _Pragma("unroll")                                                         \
    for (int q = 0; q < 4; ++q) {                                             \
      int ab = pb + ((2 * q + wr) * 32 + fr) * 128;                           \
      short8 a0 = *(const short8*)(smem + ab + koff0);                        \
      short8 a1 = *(const short8*)(smem + ab + koff1);                        \
      short8 a2 = *(const short8*)(smem + ab + 2048 + koff0);                 \
      short8 a3 = *(const short8*)(smem + ab + 2048 + koff1);                 \
      if (q == 0) {            /* stage A(t+2) FIRST in tile's VMEM order */  \
        stage_A((T_) + 2);                                                    \
        FENCE();                                                              \
      }                                                                       \
      if (q == 1) {  /* coalesced B prefetch for T_+1, other parity */        \
        int ts = (T_) + 1 < NT ? (T_) + 1 : NT - 1;                           \
        size_t tb = (size_t)(2 * ts) * 262144u;                               \
        _Pragma("unroll")                                                     \
        for (int n = 0; n < 4; ++n) {                                         \
          BN[n][0] = *(const short8*)(bbp[n] + tb);                           \
          BN[n][1] = *(const short8*)(bbp[n] + tb + 262144);                  \
        }                                                                     \
      }                                                                       \
      __builtin_amdgcn_s_setprio(1);                                          \
      _Pragma("unroll")                                                       \
      for (int n = 0; n < 4; ++n) {                                           \
        acc[2 * q][n] = __builtin_amdgcn_mfma_f32_16x16x32_bf16(              \
            __builtin_bit_cast(bf16x8, a0), __builtin_bit_cast(bf16x8, BC[n][0]),\
            acc[2 * q][n], 0, 0, 0);                                          \
        acc[2 * q + 1][n] = __builtin_amdgcn_mfma_f32_16x16x32_bf16(          \
            __builtin_bit_cast(bf16x8, a2), __builtin_bit_cast(bf16x8, BC[n][0]),\
            acc[2 * q + 1][n], 0, 0, 0);                                      \
      }                                                                       \
      _Pragma("unroll")                                                       \
      for (int n = 0; n < 4; ++n) {                                           \
        acc[2 * q][n] = __builtin_amdgcn_mfma_f32_16x16x32_bf16(              \
            __builtin_bit_cast(bf16x8, a1), __builtin_bit_cast(bf16x8, BC[n][1]),\
            acc[2 * q][n], 0, 0, 0);                                          \
        acc[2 * q + 1][n] = __builtin_amdgcn_mfma_f32_16x16x32_bf16(          \
            __builtin_bit_cast(bf16x8, a3), __builtin_bit_cast(bf16x8, BC[n][1]),\
            acc[2 * q + 1][n], 0, 0, 0);                                      \
      }                                                                       \
      __builtin_amdgcn_s_setprio(0);                                          \
    }                                                                         \
  }

  for (int t = 0; t < NT; t += 2) {
    TILE(t, 1, bfrE, bfrO)       // even: gate + barrier
    TILE(t + 1, 0, bfrO, bfrE)   // odd: free-run
  }
#undef TILE

  // ---- fused LSTM epilogue (acc[m][n]: n = gate) ----
  int col = hcol0 + wc * 16 + fr;
  float bi = bias[col], bf_ = bias[1024 + col];
  float bo = bias[2048 + col], bc = bias[3072 + col];
#pragma unroll
  for (int m = 0; m < 8; ++m) {
    int row0 = brow0 + (2 * (m >> 1) + wr) * 32 + (m & 1) * 16 + ((lane >> 4) << 2);
#pragma unroll
    for (int j = 0; j < 4; ++j) {
      size_t idx = (size_t)(row0 + j) * 1024 + col;
      float i_ = fast_sigm(acc[m][0][j] + bi);
      float f_ = fast_sigm(acc[m][1][j] + bf_);
      float o_ = fast_sigm(acc[m][2][j] + bo);
      float ch = fast_tanh(acc[m][3][j] + bc);
      float cn = i_ * ch + f_ * c0[idx];
      out_c[idx] = cn;
      out_h[idx] = o_ * fast_tanh(cn);
    }
  }
}

// Fallback if ws too small (not expected; ws >= 160MB confirmed in round 1).
__global__ __launch_bounds__(256) void lstm_naive(
    const float* __restrict__ y, const float* __restrict__ ctx,
    const float* __restrict__ c0, const float* __restrict__ h0,
    const float* __restrict__ W, const float* __restrict__ U,
    const float* __restrict__ C, const float* __restrict__ b,
    float* __restrict__ out_c, float* __restrict__ out_h) {
  size_t t = (size_t)blockIdx.x * blockDim.x + threadIdx.x;
  if (t >= (size_t)Bn * Hn) return;
  int row = (int)(t >> 10), col = (int)(t & 1023);
  float g[4];
#pragma unroll
  for (int gg = 0; gg < 4; ++gg) {
    int wrow = gg * 1024 + col;
    float s = b[wrow];
    const float* yr = y + (size_t)row * 1024;
    const float* Wr = W + (size_t)wrow * 1024;
    for (int k = 0; k < 1024; ++k) s += yr[k] * Wr[k];
    const float* hr = h0 + (size_t)row * 1024;
    const float* Ur = U + (size_t)wrow * 1024;
    for (int k = 0; k < 1024; ++k) s += hr[k] * Ur[k];
    const float* cr = ctx + (size_t)row * 2048;
    const float* Cr = C + (size_t)wrow * 2048;
    for (int k = 0; k < 2048; ++k) s += cr[k] * Cr[k];
    g[gg] = s;
  }
  float i_ = fast_sigm(g[0]), f_ = fast_sigm(g[1]);
  float o_ = fast_sigm(g[2]), ch = fast_tanh(g[3]);
  float cn = i_ * ch + f_ * c0[t];
  out_c[t] = cn;
  out_h[t] = o_ * fast_tanh(cn);
}

extern "C" void kernel_launch(void* const* d_in, const int* in_sizes, int n_in,
                              void* d_out, int out_size, void* d_ws, size_t ws_size,
                              hipStream_t stream) {
  const float* y   = (const float*)d_in[0];
  const float* ctx = (const float*)d_in[1];
  const float* c0  = (const float*)d_in[2];
  const float* h0  = (const float*)d_in[3];
  const float* W   = (const float*)d_in[4];
  const float* U   = (const float*)d_in[5];
  const float* C   = (const float*)d_in[6];
  const float* b   = (const float*)d_in[7];
  float* out = (float*)d_out;
  float* out_c = out;
  float* out_h = out + (size_t)Bn * Hn;

  const size_t needX = (size_t)Bn * KT * 2;
  const size_t needW = (size_t)(4 * Hn) * KT * 2;

  if (ws_size >= needX + needW) {
    unsigned short* Xb = (unsigned short*)d_ws;
    unsigned short* Wb = (unsigned short*)((char*)d_ws + needX);
    cvt_concat_k<<<2048, 256, 0, stream>>>(y, h0, ctx, Xb, (long long)Bn * 512);
    cvt_pack_w<<<2048, 256, 0, stream>>>(W, U, C, Wb,
                                         (long long)(4 * Hn) * KT / 8);
    (void)hipFuncSetAttribute((const void*)lstm_gemm,
                              hipFuncAttributeMaxDynamicSharedMemorySize, 131072);
    lstm_gemm<<<1024, 512, 131072, stream>>>(Xb, Wb, b, c0, out_c, out_h);
  } else {
    lstm_naive<<<(Bn * Hn + 255) / 256, 256, 0, stream>>>(y, ctx, c0, h0, W, U, C,
                                                          b, out_c, out_h);
  }
}

// Round 15
// 593.407 us; speedup vs baseline: 4.7804x; 1.0185x over previous
//
#include <hip/hip_runtime.h>
#include <hip/hip_bf16.h>
#include <stdint.h>

typedef __attribute__((ext_vector_type(8))) short short8;
typedef __attribute__((ext_vector_type(8))) unsigned short ushort8;
typedef __attribute__((ext_vector_type(4))) float f32x4;
typedef __attribute__((ext_vector_type(8))) __bf16 bf16x8;

#define GAS __attribute__((address_space(1)))
#define LAS __attribute__((address_space(3)))

static constexpr int Bn = 16384;   // batch
static constexpr int Hn = 1024;    // hidden
static constexpr int KT = 4096;    // IN + H + CTX (concat K)
static constexpr int NT = KT / 64; // 64 K-tiles

#define SBAR()   __builtin_amdgcn_s_barrier()
#define VMCNT(n) asm volatile("s_waitcnt vmcnt(" #n ")" ::: "memory")
#define FENCE()  asm volatile("" ::: "memory")

__device__ __forceinline__ unsigned short f2bf(float f) {
  unsigned u = __builtin_bit_cast(unsigned, f);
  u = (u + 0x7FFFu + ((u >> 16) & 1u)) >> 16;   // RNE
  return (unsigned short)u;
}

__device__ __forceinline__ float fast_sigm(float x) {
  return __builtin_amdgcn_rcpf(1.f + __expf(-x));
}
__device__ __forceinline__ float fast_tanh(float x) {
  return 1.f - 2.f * __builtin_amdgcn_rcpf(__expf(2.f * x) + 1.f);
}

// Concat-convert 3 fp32 sources (widths 1024,1024,2048) into bf16 [rows][4096].
__global__ __launch_bounds__(256) void cvt_concat_k(
    const float* __restrict__ s0, const float* __restrict__ s1,
    const float* __restrict__ s2, unsigned short* __restrict__ dst,
    long long n8) {
  long long stride = (long long)gridDim.x * blockDim.x;
  for (long long g = (long long)blockIdx.x * blockDim.x + threadIdx.x; g < n8;
       g += stride) {
    long long row = g >> 9;
    int cg = (int)(g & 511) << 3;
    const float* src;
    if (cg < 1024)      src = s0 + row * 1024 + cg;
    else if (cg < 2048) src = s1 + row * 1024 + (cg - 1024);
    else                src = s2 + row * 2048 + (cg - 2048);
    float4 f0 = *(const float4*)src;
    float4 f1 = *(const float4*)(src + 4);
    ushort8 o;
    o[0] = f2bf(f0.x); o[1] = f2bf(f0.y); o[2] = f2bf(f0.z); o[3] = f2bf(f0.w);
    o[4] = f2bf(f1.x); o[5] = f2bf(f1.y); o[6] = f2bf(f1.z); o[7] = f2bf(f1.w);
    *(ushort8*)(dst + (g << 3)) = o;
  }
}

// Pack W|U|C into 16x16x32-MFMA B-frag records — WRITE-COALESCED (r10).
__global__ __launch_bounds__(256) void cvt_pack_w(
    const float* __restrict__ s0, const float* __restrict__ s1,
    const float* __restrict__ s2, unsigned short* __restrict__ dst,
    long long ntot) {
  long long stride = (long long)gridDim.x * blockDim.x;
  for (long long g = (long long)blockIdx.x * blockDim.x + threadIdx.x; g < ntot;
       g += stride) {
    int li = (int)(g & 63);
    long long rec = g >> 6;
    int cb = (int)(rec & 255);
    int k32 = (int)(rec >> 8);
    int fr = li & 15, ksl = li >> 4;
    int row = cb * 16 + fr;            // W-concat row = gemm column
    int k0 = k32 * 32 + ksl * 8;
    const float* src;
    if (k0 < 1024)      src = s0 + (size_t)row * 1024 + k0;
    else if (k0 < 2048) src = s1 + (size_t)row * 1024 + (k0 - 1024);
    else                src = s2 + (size_t)row * 2048 + (k0 - 2048);
    float4 f0 = *(const float4*)src;
    float4 f1 = *(const float4*)(src + 4);
    ushort8 o;
    o[0] = f2bf(f0.x); o[1] = f2bf(f0.y); o[2] = f2bf(f0.z); o[3] = f2bf(f0.w);
    o[4] = f2bf(f1.x); o[5] = f2bf(f1.y); o[6] = f2bf(f1.z); o[7] = f2bf(f1.w);
    *(ushort8*)(dst + (g << 3)) = o;
  }
}

// 256x256 GEMM + fused LSTM. 16x16x32 MFMA, 8 waves (2M x 4N).  [r10 core]
// r15 refinements (ledger-preserving):
//  (a) B prefetch split: k0-slice x4 at q1, k1-slice x4 at q2 (smoother VMEM
//      issue; per-tile VMEM order/count class unchanged -> VMCNT(12) audit
//      holds verbatim).
//  (b) Tail c0 prefetch: the dummy clamped A-stages of the last 2 tiles
//      (dead-buffer writes) are REPLACED by DMA of the block's c0 panel
//      (2 x 32KB chunks -> the two dead buffers; same 4 gload_lds per call,
//      ledger byte-identical). Epilogue reads c0 from LDS after one post-loop
//      VMCNT(0)+SBAR, removing the latency-exposed global c0 burst.
// A: LDS via global_load_lds, 3 rotating 32KB buffers, staged 2 tiles ahead,
//    st_16x32 both-sides swizzle (conflict-free). B: frag-major packed global.
// Sync: ONE {VMCNT(12); s_barrier} per tile; never vmcnt(0) mid-loop.
__global__ __launch_bounds__(512, 2) void lstm_gemm(
    const unsigned short* __restrict__ X, const unsigned short* __restrict__ Wp,
    const float* __restrict__ bias, const float* __restrict__ c0,
    float* __restrict__ out_c, float* __restrict__ out_h) {
  extern __shared__ char smem[];  // 3 x 32KB A buffers

  int bid = blockIdx.x;
  int swz = (bid & 7) * 128 + (bid >> 3);  // 1024 blocks, 8 XCDs, bijective
  int mblk = swz >> 4, cblk = swz & 15;    // 16 consecutive share A-panel
  int brow0 = mblk * 256;
  int hcol0 = cblk * 64;

  int tid = threadIdx.x;
  int lane = tid & 63, wid = tid >> 6;
  int wr = wid >> 2, wc = wid & 3;  // 2M x 4N wave grid

  const char* Xc = (const char*)X;
  const char* Wpc = (const char*)Wp;

  // ---- A staging: inverse-swizzled global source, linear LDS dest ----
  int rr = tid >> 3;                                        // 0..63
  uint32_t cbyte = (uint32_t)(((tid & 7) * 16) ^ ((rr & 7) << 4));
  uint32_t aoffj[4];
#pragma unroll
  for (int j = 0; j < 4; ++j)
    aoffj[j] = (uint32_t)(brow0 + j * 64 + rr) * (KT * 2) + cbyte;

  // Stage slot: tt < NT -> A(tt) into dbuf (32KB = 4 x gload_lds).
  //             tt >= NT (last 2 tiles' dead slots) -> c0 chunk (tt-NT):
  //             rows chunk*128..+127, cols hcol0..+63, fp32 -> 32KB linear.
  auto stage_slot = [&](int tt, int dbuf) {
    if (tt < NT) {
#pragma unroll
      for (int j = 0; j < 4; ++j) {
        const char* src = Xc + aoffj[j] + (uint32_t)tt * 128u;
        char* dst = smem + dbuf * 32768 + j * 8192 + wid * 1024;
        __builtin_amdgcn_global_load_lds((const GAS unsigned int*)src,
                                         (LAS unsigned int*)dst, 16, 0, 0);
      }
    } else {
      int chunk = tt - NT;                    // 0 or 1
      int base = chunk ? 65536 : 32768;      // dead buffers 1 and 2
#pragma unroll
      for (int j = 0; j < 4; ++j) {
        int srow = chunk * 128 + j * 32 + (tid >> 4);
        int scol = (tid & 15) * 4;
        const char* src =
            (const char*)(c0 + (size_t)(brow0 + srow) * 1024 + hcol0 + scol);
        char* dst = smem + base + j * 8192 + wid * 1024;
        __builtin_amdgcn_global_load_lds((const GAS unsigned int*)src,
                                         (LAS unsigned int*)dst, 16, 0, 0);
      }
    }
  };

  // ---- A ds_read swizzled offsets ----
  int kg = (lane >> 4) << 4;
  int sw = (lane & 7) << 4;
  int koff0 = kg ^ sw;
  int koff1 = (64 + kg) ^ sw;
  int fr = lane & 15;

  // ---- B frag-major per-lane base pointers (gate n) ----
  const char* bbp[4];
#pragma unroll
  for (int n = 0; n < 4; ++n) {
    int cb = n * 64 + cblk * 4 + wc;
    bbp[n] = Wpc + ((size_t)cb * 64 + lane) * 16;
  }

  f32x4 acc[8][4] = {};
  short8 bfrE[4][2], bfrO[4][2];   // B frag parity sets [n][k-slice]

  // ---- prologue: A(0); fence; B(0)->E + A(1)   (16 VMEM, A(0) oldest) ----
  stage_slot(0, 0);
  FENCE();
#pragma unroll
  for (int n = 0; n < 4; ++n) {
    bfrE[n][0] = *(const short8*)(bbp[n]);
    bfrE[n][1] = *(const short8*)(bbp[n] + 262144);
  }
  stage_slot(1, 1);

  int bufA = 0;

#define TILE(T_, BC, BN)                                                      \
  {                                                                           \
    VMCNT(12);                                                                \
    SBAR();                                                                   \
    int pb = bufA * 32768;                                                    \
    int stg = bufA + 2; if (stg >= 3) stg -= 3;                               \
    _Pragma("unroll")                                                         \
    for (int q = 0; q < 4; ++q) {                                             \
      int ab = pb + ((2 * q + wr) * 32 + fr) * 128;                           \
      short8 a0 = *(const short8*)(smem + ab + koff0);                        \
      short8 a1 = *(const short8*)(smem + ab + koff1);                        \
      short8 a2 = *(const short8*)(smem + ab + 2048 + koff0);                 \
      short8 a3 = *(const short8*)(smem + ab + 2048 + koff1);                 \
      if (q == 1) {  /* B(t+1) k0-slice x4 */                                 \
        int ts = (T_) + 1 < NT ? (T_) + 1 : NT - 1;                           \
        size_t tb = (size_t)(2 * ts) * 262144u;                               \
        _Pragma("unroll")                                                     \
        for (int n = 0; n < 4; ++n)                                           \
          BN[n][0] = *(const short8*)(bbp[n] + tb);                           \
      }                                                                       \
      if (q == 2) {  /* B(t+1) k1-slice x4 */                                 \
        int ts = (T_) + 1 < NT ? (T_) + 1 : NT - 1;                           \
        size_t tb = (size_t)(2 * ts) * 262144u;                               \
        _Pragma("unroll")                                                     \
        for (int n = 0; n < 4; ++n)                                           \
          BN[n][1] = *(const short8*)(bbp[n] + tb + 262144);                  \
      }                                                                       \
      if (q == 3) stage_slot((T_) + 2, stg);                                  \
      __builtin_amdgcn_s_setprio(1);                                          \
      _Pragma("unroll")                                                       \
      for (int n = 0; n < 4; ++n) {                                           \
        acc[2 * q][n] = __builtin_amdgcn_mfma_f32_16x16x32_bf16(              \
            __builtin_bit_cast(bf16x8, a0), __builtin_bit_cast(bf16x8, BC[n][0]),\
            acc[2 * q][n], 0, 0, 0);                                          \
        acc[2 * q + 1][n] = __builtin_amdgcn_mfma_f32_16x16x32_bf16(          \
            __builtin_bit_cast(bf16x8, a2), __builtin_bit_cast(bf16x8, BC[n][0]),\
            acc[2 * q + 1][n], 0, 0, 0);                                      \
      }                                                                       \
      _Pragma("unroll")                                                       \
      for (int n = 0; n < 4; ++n) {                                           \
        acc[2 * q][n] = __builtin_amdgcn_mfma_f32_16x16x32_bf16(              \
            __builtin_bit_cast(bf16x8, a1), __builtin_bit_cast(bf16x8, BC[n][1]),\
            acc[2 * q][n], 0, 0, 0);                                          \
        acc[2 * q + 1][n] = __builtin_amdgcn_mfma_f32_16x16x32_bf16(          \
            __builtin_bit_cast(bf16x8, a3), __builtin_bit_cast(bf16x8, BC[n][1]),\
            acc[2 * q + 1][n], 0, 0, 0);                                      \
      }                                                                       \
      __builtin_amdgcn_s_setprio(0);                                          \
    }                                                                         \
    bufA = bufA + 1; if (bufA >= 3) bufA = 0;                                 \
  }

  for (int t = 0; t < NT; t += 2) {
    TILE(t, bfrE, bfrO)
    TILE(t + 1, bfrO, bfrE)
  }
#undef TILE

  // ---- drain c0 DMA and publish LDS across waves ----
  VMCNT(0);
  SBAR();

  // ---- fused LSTM epilogue (acc[m][n]: n = gate); c0 from LDS ----
  int col = hcol0 + wc * 16 + fr;
  float bi = bias[col], bf_ = bias[1024 + col];
  float bo = bias[2048 + col], bc = bias[3072 + col];
#pragma unroll
  for (int m = 0; m < 8; ++m) {
    int rrel0 = (2 * (m >> 1) + wr) * 32 + (m & 1) * 16 + ((lane >> 4) << 2);
#pragma unroll
    for (int j = 0; j < 4; ++j) {
      int r = rrel0 + j;                       // block-relative row 0..255
      size_t idx = (size_t)(brow0 + r) * 1024 + col;
      float c0v = *(const float*)(smem + 32768 + (r >> 7) * 32768 +
                                  (r & 127) * 256 + (wc * 16 + fr) * 4);
      float i_ = fast_sigm(acc[m][0][j] + bi);
      float f_ = fast_sigm(acc[m][1][j] + bf_);
      float o_ = fast_sigm(acc[m][2][j] + bo);
      float ch = fast_tanh(acc[m][3][j] + bc);
      float cn = i_ * ch + f_ * c0v;
      out_c[idx] = cn;
      out_h[idx] = o_ * fast_tanh(cn);
    }
  }
}

// Fallback if ws too small (not expected; ws >= 160MB confirmed in round 1).
__global__ __launch_bounds__(256) void lstm_naive(
    const float* __restrict__ y, const float* __restrict__ ctx,
    const float* __restrict__ c0, const float* __restrict__ h0,
    const float* __restrict__ W, const float* __restrict__ U,
    const float* __restrict__ C, const float* __restrict__ b,
    float* __restrict__ out_c, float* __restrict__ out_h) {
  size_t t = (size_t)blockIdx.x * blockDim.x + threadIdx.x;
  if (t >= (size_t)Bn * Hn) return;
  int row = (int)(t >> 10), col = (int)(t & 1023);
  float g[4];
#pragma unroll
  for (int gg = 0; gg < 4; ++gg) {
    int wrow = gg * 1024 + col;
    float s = b[wrow];
    const float* yr = y + (size_t)row * 1024;
    const float* Wr = W + (size_t)wrow * 1024;
    for (int k = 0; k < 1024; ++k) s += yr[k] * Wr[k];
    const float* hr = h0 + (size_t)row * 1024;
    const float* Ur = U + (size_t)wrow * 1024;
    for (int k = 0; k < 1024; ++k) s += hr[k] * Ur[k];
    const float* cr = ctx + (size_t)row * 2048;
    const float* Cr = C + (size_t)wrow * 2048;
    for (int k = 0; k < 2048; ++k) s += cr[k] * Cr[k];
    g[gg] = s;
  }
  float i_ = fast_sigm(g[0]), f_ = fast_sigm(g[1]);
  float o_ = fast_sigm(g[2]), ch = fast_tanh(g[3]);
  float cn = i_ * ch + f_ * c0[t];
  out_c[t] = cn;
  out_h[t] = o_ * fast_tanh(cn);
}

extern "C" void kernel_launch(void* const* d_in, const int* in_sizes, int n_in,
                              void* d_out, int out_size, void* d_ws, size_t ws_size,
                              hipStream_t stream) {
  const float* y   = (const float*)d_in[0];
  const float* ctx = (const float*)d_in[1];
  const float* c0  = (const float*)d_in[2];
  const float* h0  = (const float*)d_in[3];
  const float* W   = (const float*)d_in[4];
  const float* U   = (const float*)d_in[5];
  const float* C   = (const float*)d_in[6];
  const float* b   = (const float*)d_in[7];
  float* out = (float*)d_out;
  float* out_c = out;
  float* out_h = out + (size_t)Bn * Hn;

  const size_t needX = (size_t)Bn * KT * 2;
  const size_t needW = (size_t)(4 * Hn) * KT * 2;

  if (ws_size >= needX + needW) {
    unsigned short* Xb = (unsigned short*)d_ws;
    unsigned short* Wb = (unsigned short*)((char*)d_ws + needX);
    cvt_concat_k<<<2048, 256, 0, stream>>>(y, h0, ctx, Xb, (long long)Bn * 512);
    cvt_pack_w<<<2048, 256, 0, stream>>>(W, U, C, Wb,
                                         (long long)(4 * Hn) * KT / 8);
    (void)hipFuncSetAttribute((const void*)lstm_gemm,
                              hipFuncAttributeMaxDynamicSharedMemorySize, 98304);
    lstm_gemm<<<1024, 512, 98304, stream>>>(Xb, Wb, b, c0, out_c, out_h);
  } else {
    lstm_naive<<<(Bn * Hn + 255) / 256, 256, 0, stream>>>(y, ctx, c0, h0, W, U, C,
                                                          b, out_c, out_h);
  }
}